// Round 1
// baseline (16736.693 us; speedup 1.0000x reference)
//
#include <hip/hip_runtime.h>

#define TT 1024
#define BB 64
#define DD 512
#define HH 512
#define GBg 8      // batch groups (8 batches each)
#define GHs 32     // hidden slices (16 units each)
#define BPG 8
#define UPS 16
#define NTHR 256

typedef short s8v __attribute__((ext_vector_type(8)));
typedef float f4v __attribute__((ext_vector_type(4)));

// XOR swizzle for the A tile: row-major [16][1024] bf16 would be a 16-way
// bank conflict on ds_read_b128 (row stride 2048B); XOR bit4 with row&7
// spreads 8 rows across 8 distinct 16B slots (rows r, r+8 share: 2-way = free).
#define ASWZ(row, kbyte) ((((row) * 2048) + (kbyte)) ^ (((row) & 7) << 4))

static __device__ __forceinline__ unsigned short f2bf(float f) {
  union { float f; unsigned int u; } v; v.f = f;
  unsigned int r = v.u + 0x7FFFu + ((v.u >> 16) & 1u);  // RNE
  return (unsigned short)(r >> 16);
}

__global__ void __launch_bounds__(512, 1) qlstm_init(int* flags) {
  if ((int)threadIdx.x < GBg * 64)
    __hip_atomic_store(flags + threadIdx.x, 0, __ATOMIC_RELAXED,
                       __HIP_MEMORY_SCOPE_AGENT);
}

struct SMem {
  char ab[16 * 1024 * 2];   // A tile [16 rows][1024 k] bf16, swizzled (32 KB)
  float zp[4][16][64];      // per-wave K-split partial z (16 KB)
  float cst[BPG * UPS];     // cell state (fp32)
};

__global__ void __launch_bounds__(NTHR, 1) qlstm_main(
    const float* __restrict__ X,
    const float* __restrict__ Wf, const float* __restrict__ bfp,
    const float* __restrict__ Wi, const float* __restrict__ bip,
    const float* __restrict__ Wg, const float* __restrict__ bgp,
    const float* __restrict__ Wo, const float* __restrict__ bop,
    const float* __restrict__ phase,
    float* __restrict__ out, int* __restrict__ flags,
    float* __restrict__ hbuf) {
  __shared__ SMem sm;
  const int tid   = threadIdx.x;
  const int wv    = tid >> 6;
  const int lane  = tid & 63;
  const int group = blockIdx.x & 7;    // %8 -> (hopefully) per-XCD grouping
  const int slice = blockIdx.x >> 3;
  const int b0 = group * BPG;          // global batch base
  const int u0 = slice * UPS;          // global hidden-unit base

  // ---- persistent weight fragments (MFMA B operand) in registers ----
  // wave wv owns K rows [wv*256, wv*256+256); cols: cf*16+(lane&15) where
  // cf = gate index (f,i,g,o). B frag: lane holds B[k=(lane>>4)*8+j][n=lane&15].
  const float* Wm[4] = {Wf, Wi, Wg, Wo};
  const int ucol  = u0 + (lane & 15);
  const int krow0 = wv * 256 + ((lane >> 4) << 3);
  s8v wreg[8][4];
#pragma unroll
  for (int kk = 0; kk < 8; ++kk) {
#pragma unroll
    for (int cf = 0; cf < 4; ++cf) {
      const float* Wp = Wm[cf] + (size_t)(krow0 + kk * 32) * HH + ucol;
      s8v w;
#pragma unroll
      for (int j = 0; j < 8; ++j) w[j] = (short)f2bf(Wp[(size_t)j * HH]);
      wreg[kk][cf] = w;
    }
  }

  float breg[4] = {0.f, 0.f, 0.f, 0.f};
  if (tid < BPG * UPS) {
    const int u = u0 + (tid & 15);
    breg[0] = bfp[u] + phase[u];
    breg[1] = bip[u] + phase[u];
    breg[2] = bgp[u] + phase[u];
    breg[3] = bop[u] + phase[u];
  }

  // zero A tile (pad rows 8..15 + h region for t=0) and cell state
  for (int i = tid; i < (int)(sizeof(sm.ab) / 16); i += NTHR)
    ((int4*)sm.ab)[i] = make_int4(0, 0, 0, 0);
  if (tid < BPG * UPS) sm.cst[tid] = 0.f;
  __syncthreads();

  int* myflag = flags + group * 64 + slice;
  int* pollp  = flags + group * 64 + (lane & 31);

  for (int t = 0; t < TT; ++t) {
    // ---- x-part of A: global loads issued before the poll (h-independent) --
    float4 xpre[4];
    {
      const float4* Xr = (const float4*)(X + ((size_t)t * BB + b0) * DD);
#pragma unroll
      for (int i = 0; i < 4; ++i) {
        const int idx = tid + i * NTHR;          // 0..1023
        xpre[i] = Xr[(idx >> 7) * (DD / 4) + (idx & 127)];
      }
#pragma unroll
      for (int i = 0; i < 4; ++i) {
        const int idx = tid + i * NTHR;
        const int row = idx >> 7, d4 = idx & 127;
        ushort4 bv;
        bv.x = f2bf(xpre[i].x); bv.y = f2bf(xpre[i].y);
        bv.z = f2bf(xpre[i].z); bv.w = f2bf(xpre[i].w);
        *(ushort4*)(sm.ab + ASWZ(row, d4 * 8)) = bv;
      }
    }
    // ---- wait until all 32 slices of this group published h_{t-1} ----
    if (t > 0) {
      for (;;) {
        const int v = __hip_atomic_load(pollp, __ATOMIC_ACQUIRE,
                                        __HIP_MEMORY_SCOPE_AGENT);
        if (__all(v >= t)) break;
        __builtin_amdgcn_s_sleep(1);
      }
      // h-part of A (agent-scope loads: coherent across XCDs)
      const float* Hb = hbuf + ((size_t)((t - 1) & 1) * BB + b0) * HH;
#pragma unroll
      for (int i = 0; i < 16; ++i) {
        const int idx = tid + i * NTHR;          // 0..4095
        const int row = idx >> 9, d = idx & 511;
        const float hv = __hip_atomic_load((float*)(Hb + row * HH + d),
                                           __ATOMIC_RELAXED,
                                           __HIP_MEMORY_SCOPE_AGENT);
        *(unsigned short*)(sm.ab + ASWZ(row, 1024 + d * 2)) = f2bf(hv);
      }
    }
    __syncthreads();

    // ---- MFMA over this wave's K slice (K=256 = 8 steps of 32) ----
    f4v acc[4] = {{0.f, 0.f, 0.f, 0.f}, {0.f, 0.f, 0.f, 0.f},
                  {0.f, 0.f, 0.f, 0.f}, {0.f, 0.f, 0.f, 0.f}};
    const int abase = (wv * 256 + ((lane >> 4) << 3)) * 2;
    const int arow  = lane & 15;
#pragma unroll
    for (int kk = 0; kk < 8; ++kk) {
      const s8v af = *(const s8v*)(sm.ab + ASWZ(arow, abase + kk * 64));
#pragma unroll
      for (int cf = 0; cf < 4; ++cf)
        acc[cf] = __builtin_amdgcn_mfma_f32_16x16x32_bf16(af, wreg[kk][cf],
                                                          acc[cf], 0, 0, 0);
    }
    // C/D layout: col = lane&15, row = (lane>>4)*4 + i  [m89-verified]
#pragma unroll
    for (int cf = 0; cf < 4; ++cf)
#pragma unroll
      for (int i = 0; i < 4; ++i)
        sm.zp[wv][((lane >> 4) << 2) + i][cf * 16 + (lane & 15)] = acc[cf][i];
    __syncthreads();

    // ---- reduce K-split partials, gates, state update, publish h ----
    if (tid < BPG * UPS) {
      const int b = tid >> 4, u = tid & 15;
      const float z0 = sm.zp[0][b][u]      + sm.zp[1][b][u]      +
                       sm.zp[2][b][u]      + sm.zp[3][b][u]      + breg[0];
      const float z1 = sm.zp[0][b][16 + u] + sm.zp[1][b][16 + u] +
                       sm.zp[2][b][16 + u] + sm.zp[3][b][16 + u] + breg[1];
      const float z2 = sm.zp[0][b][32 + u] + sm.zp[1][b][32 + u] +
                       sm.zp[2][b][32 + u] + sm.zp[3][b][32 + u] + breg[2];
      const float z3 = sm.zp[0][b][48 + u] + sm.zp[1][b][48 + u] +
                       sm.zp[2][b][48 + u] + sm.zp[3][b][48 + u] + breg[3];
      const float fg = 1.f / (1.f + __expf(-z0));
      const float ig = 1.f / (1.f + __expf(-z1));
      const float gg = 1.f - 2.f / (__expf(2.f * z2) + 1.f);
      const float og = 1.f / (1.f + __expf(-z3));
      const float cn = fg * sm.cst[tid] + ig * gg;
      sm.cst[tid] = cn;
      const float h = og * (1.f - 2.f / (__expf(2.f * cn) + 1.f));
      const int bgl = b0 + b, ugl = u0 + u;
      out[(size_t)t * (BB * HH) + bgl * HH + ugl] = h;
      __hip_atomic_store(hbuf + ((size_t)(t & 1) * BB + bgl) * HH + ugl, h,
                         __ATOMIC_RELAXED, __HIP_MEMORY_SCOPE_AGENT);
      if (t == TT - 1) {
        out[(size_t)TT * BB * HH + bgl * HH + ugl] = h;                 // hx
        out[(size_t)TT * BB * HH + BB * HH + bgl * HH + ugl] = cn;      // cx
      }
    }
    __syncthreads();  // drains vmcnt: all agent-atomic h stores are visible
    if (tid == 0)
      __hip_atomic_store(myflag, t + 1, __ATOMIC_RELEASE,
                         __HIP_MEMORY_SCOPE_AGENT);
  }
}

extern "C" void kernel_launch(void* const* d_in, const int* in_sizes, int n_in,
                              void* d_out, int out_size, void* d_ws,
                              size_t ws_size, hipStream_t stream) {
  const float* X   = (const float*)d_in[0];
  const float* Wf  = (const float*)d_in[1];
  const float* bfp = (const float*)d_in[2];
  const float* Wi  = (const float*)d_in[3];
  const float* bip = (const float*)d_in[4];
  const float* Wg  = (const float*)d_in[5];
  const float* bgp = (const float*)d_in[6];
  const float* Wo  = (const float*)d_in[7];
  const float* bop = (const float*)d_in[8];
  const float* ph  = (const float*)d_in[9];
  float* out = (float*)d_out;

  // ws layout: [0,2KB) flags[8][64]; [8KB, 8KB+256KB) fp32 h double-buffer
  int*   flags = (int*)d_ws;
  float* hbuf  = (float*)((char*)d_ws + 8192);

  qlstm_init<<<1, 512, 0, stream>>>(flags);   // reset flags each launch
  qlstm_main<<<GBg * GHs, NTHR, 0, stream>>>(X, Wf, bfp, Wi, bip, Wg, bgp, Wo,
                                             bop, ph, out, flags, hbuf);
}

// Round 2
// 3465.738 us; speedup vs baseline: 4.8292x; 4.8292x over previous
//
#include <hip/hip_runtime.h>

#define TT 1024
#define BB 64
#define DD 512
#define HH 512
#define NG 4       // batch groups (16 batches each)
#define BPG 16
#define NS 32      // hidden slices (16 units each)
#define UPS 16
#define NTHR 256

typedef short s8v __attribute__((ext_vector_type(8)));
typedef float f4v __attribute__((ext_vector_type(4)));
typedef int i4v __attribute__((ext_vector_type(4)));

// XOR swizzle: [16][1024] bf16 row-major is a 32-way conflict on ds_read_b128;
// XOR bit4 with row&7 spreads 8 rows over 8 distinct 16B slots (2-way = free).
#define ASWZ(row, kbyte) ((((row) * 2048) + (kbyte)) ^ (((row) & 7) << 4))

static __device__ __forceinline__ unsigned short f2bf(float f) {
  union { float f; unsigned int u; } v; v.f = f;
  unsigned int r = v.u + 0x7FFFu + ((v.u >> 16) & 1u);  // RNE
  return (unsigned short)(r >> 16);
}

// Coherent (L3 / coherence-point) accesses: sc0 sc1 bypass L1+L2, no
// compiler-inserted buffer_wbl2 / buffer_inv (the R1 killer).
static __device__ __forceinline__ i4v ld_b128_cohere(const void* p) {
  i4v r;
  asm volatile("global_load_dwordx4 %0, %1, off sc0 sc1"
               : "=v"(r) : "v"(p) : "memory");
  return r;
}
static __device__ __forceinline__ int ld_b32_cohere(const void* p) {
  int r;
  asm volatile("global_load_dword %0, %1, off sc0 sc1\n\t"
               "s_waitcnt vmcnt(0)"
               : "=v"(r) : "v"(p) : "memory");
  return r;
}
static __device__ __forceinline__ void st_b32_cohere(void* p, unsigned int v) {
  asm volatile("global_store_dword %0, %1, off sc0 sc1"
               :: "v"(p), "v"(v) : "memory");
}
static __device__ __forceinline__ unsigned int cvtpk_bf16(float lo, float hi) {
  unsigned int r;
  asm("v_cvt_pk_bf16_f32 %0, %1, %2" : "=v"(r) : "v"(lo), "v"(hi));
  return r;
}

__global__ void __launch_bounds__(256, 1) qlstm_init(int* flags) {
  // coherent store so sc0/sc1 readers in qlstm_main see zeros
  st_b32_cohere(flags + threadIdx.x, 0u);
}

struct SMem {
  char ab[16 * 1024 * 2];   // A tile [16 rows][k=0..511 x | 512..1023 h] bf16, swizzled
  float zp[4][64][17];      // K-split partials [wave][zcol][batch+pad] (~17 KB)
};

__global__ void __launch_bounds__(NTHR, 1) qlstm_main(
    const float* __restrict__ X,
    const float* __restrict__ Wf, const float* __restrict__ bfp,
    const float* __restrict__ Wi, const float* __restrict__ bip,
    const float* __restrict__ Wg, const float* __restrict__ bgp,
    const float* __restrict__ Wo, const float* __restrict__ bop,
    const float* __restrict__ phase,
    float* __restrict__ out, int* __restrict__ flags,
    unsigned short* __restrict__ hbuf) {
  __shared__ SMem sm;
  const int tid  = threadIdx.x;
  const int wv   = tid >> 6;
  const int lane = tid & 63;
  const int group = blockIdx.x & (NG - 1);
  const int slice = blockIdx.x / NG;
  const int b0 = group * BPG;
  const int u0 = slice * UPS;
  const int gb = tid >> 4;   // batch row 0..15 (gate phase / x stage)
  const int gu = tid & 15;   // unit 0..15

  // ---- persistent weight fragments (MFMA B operand): wave wv owns K rows
  // [wv*256, wv*256+256) x 64 z-cols (4 gates x 16 units). 128 VGPRs. ----
  const float* Wm[4] = {Wf, Wi, Wg, Wo};
  const int ucol  = u0 + (lane & 15);
  const int krow0 = wv * 256 + ((lane >> 4) << 3);
  s8v wreg[8][4];
#pragma unroll
  for (int kk = 0; kk < 8; ++kk) {
#pragma unroll
    for (int cf = 0; cf < 4; ++cf) {
      const float* Wp = Wm[cf] + (size_t)(krow0 + kk * 32) * HH + ucol;
      s8v w;
#pragma unroll
      for (int j = 0; j < 8; ++j) w[j] = (short)f2bf(Wp[(size_t)j * HH]);
      wreg[kk][cf] = w;
    }
  }

  const int uu = u0 + gu;
  float breg[4] = {bfp[uu] + phase[uu], bip[uu] + phase[uu],
                   bgp[uu] + phase[uu], bop[uu] + phase[uu]};
  float creg = 0.f;

  // ---- prologue: stage x[0] into LDS ----
  {
    const float4* Xr = (const float4*)(X + ((size_t)0 * BB + b0 + gb) * DD);
    float4 xv[8];
#pragma unroll
    for (int j = 0; j < 8; ++j) xv[j] = Xr[gu + 16 * j];
#pragma unroll
    for (int j = 0; j < 8; ++j) {
      uint2 pk;
      pk.x = cvtpk_bf16(xv[j].x, xv[j].y);
      pk.y = cvtpk_bf16(xv[j].z, xv[j].w);
      *(uint2*)(sm.ab + ASWZ(gb, (4 * gu + 64 * j) * 2)) = pk;
    }
  }
  __syncthreads();

  const int arow = lane & 15;
  int* myflag = flags + group * 64 + slice;
  const int* pollp = flags + group * 64 + (lane & 31);

  for (int t = 0; t < TT; ++t) {
    f4v acc[4] = {{0.f, 0.f, 0.f, 0.f}, {0.f, 0.f, 0.f, 0.f},
                  {0.f, 0.f, 0.f, 0.f}, {0.f, 0.f, 0.f, 0.f}};
    if (wv < 2 || t > 0) {
      if (wv >= 2) {
        // ---- waves 2,3 (h K-range): poll group flags, stage OWN quarter ----
        for (;;) {
          const int v = ld_b32_cohere(pollp);
          if (__all(v >= t)) break;
          __builtin_amdgcn_s_sleep(1);
        }
        const int urow  = lane & 15;
        const int ucol0 = (wv - 2) * 256 + ((lane >> 4) << 6);  // 64-unit run
        const unsigned short* hb =
            hbuf + (size_t)((t - 1) & 1) * BB * HH + (b0 + urow) * HH + ucol0;
        i4v hr[8];
#pragma unroll
        for (int j = 0; j < 8; ++j) hr[j] = ld_b128_cohere(hb + j * 8);
        asm volatile("s_waitcnt vmcnt(0)" ::: "memory");
        __builtin_amdgcn_sched_barrier(0);
#pragma unroll
        for (int j = 0; j < 8; ++j)
          *(i4v*)(sm.ab + ASWZ(urow, 1024 + (ucol0 + j * 8) * 2)) = hr[j];
        // same-wave ds_write -> ds_read: program-order at the LDS pipe; the
        // wave reads only what it staged, so no barrier needed here.
      }
      // ---- MFMA over this wave's K slice (8 chunks of 32) ----
      const int kbyte0 = wv * 512 + ((lane >> 4) << 4);
#pragma unroll
      for (int kk = 0; kk < 8; ++kk) {
        const s8v af = *(const s8v*)(sm.ab + ASWZ(arow, kbyte0 + kk * 64));
#pragma unroll
        for (int cf = 0; cf < 4; ++cf)
          acc[cf] = __builtin_amdgcn_mfma_f32_16x16x32_bf16(af, wreg[kk][cf],
                                                            acc[cf], 0, 0, 0);
      }
    }
    // ---- K-split partials -> LDS (bank-friendly [wave][col][b+pad]) ----
#pragma unroll
    for (int cf = 0; cf < 4; ++cf)
#pragma unroll
      for (int i = 0; i < 4; ++i)
        sm.zp[wv][cf * 16 + (lane & 15)][((lane >> 4) << 2) + i] = acc[cf][i];
    __syncthreads();  // bar#1

    // ---- x(t+1) prefetch loads first (latency hides under gate math) ----
    float4 xv[8];
    const bool px = (t + 1 < TT);
    if (px) {
      const float4* Xr = (const float4*)(X + ((size_t)(t + 1) * BB + b0 + gb) * DD);
#pragma unroll
      for (int j = 0; j < 8; ++j) xv[j] = Xr[gu + 16 * j];
    }
    // ---- gates: thread owns (batch gb, unit gu); c stays in register ----
    float z[4];
#pragma unroll
    for (int cf = 0; cf < 4; ++cf)
      z[cf] = sm.zp[0][cf * 16 + gu][gb] + sm.zp[1][cf * 16 + gu][gb] +
              sm.zp[2][cf * 16 + gu][gb] + sm.zp[3][cf * 16 + gu][gb] + breg[cf];
    const float fg = 1.f / (1.f + __expf(-z[0]));
    const float ig = 1.f / (1.f + __expf(-z[1]));
    const float gg = 1.f - 2.f / (__expf(2.f * z[2]) + 1.f);
    const float og = 1.f / (1.f + __expf(-z[3]));
    creg = fg * creg + ig * gg;
    const float hv = og * (1.f - 2.f / (__expf(2.f * creg) + 1.f));

    // ---- publish h first (critical path): packed bf16, coherent store ----
    const float hn = __shfl_down(hv, 1);
    if (!(gu & 1)) {
      unsigned short* hp =
          hbuf + (size_t)(t & 1) * BB * HH + (b0 + gb) * HH + (u0 + gu);
      st_b32_cohere(hp, cvtpk_bf16(hv, hn));
    }
    out[(size_t)t * (BB * HH) + (b0 + gb) * HH + (u0 + gu)] = hv;
    if (t == TT - 1) {
      out[(size_t)TT * BB * HH + (b0 + gb) * HH + (u0 + gu)] = hv;            // hx
      out[(size_t)TT * BB * HH + BB * HH + (b0 + gb) * HH + (u0 + gu)] = creg; // cx
    }
    // ---- stage x(t+1) into LDS (x-region readers are past bar#1) ----
    if (px) {
#pragma unroll
      for (int j = 0; j < 8; ++j) {
        uint2 pk;
        pk.x = cvtpk_bf16(xv[j].x, xv[j].y);
        pk.y = cvtpk_bf16(xv[j].z, xv[j].w);
        *(uint2*)(sm.ab + ASWZ(gb, (4 * gu + 64 * j) * 2)) = pk;
      }
    }
    asm volatile("s_waitcnt vmcnt(0)" ::: "memory");  // drain h stores
    __syncthreads();  // bar#2
    if (tid == 0) st_b32_cohere(myflag, (unsigned int)(t + 1));
  }
}

extern "C" void kernel_launch(void* const* d_in, const int* in_sizes, int n_in,
                              void* d_out, int out_size, void* d_ws,
                              size_t ws_size, hipStream_t stream) {
  const float* X   = (const float*)d_in[0];
  const float* Wf  = (const float*)d_in[1];
  const float* bfp = (const float*)d_in[2];
  const float* Wi  = (const float*)d_in[3];
  const float* bip = (const float*)d_in[4];
  const float* Wg  = (const float*)d_in[5];
  const float* bgp = (const float*)d_in[6];
  const float* Wo  = (const float*)d_in[7];
  const float* bop = (const float*)d_in[8];
  const float* ph  = (const float*)d_in[9];
  float* out = (float*)d_out;

  // ws: [0,1KB) flags[4][64]; [8KB, 8KB+128KB) bf16 h double-buffer
  int* flags = (int*)d_ws;
  unsigned short* hbuf = (unsigned short*)((char*)d_ws + 8192);

  qlstm_init<<<1, 256, 0, stream>>>(flags);
  qlstm_main<<<NG * NS, NTHR, 0, stream>>>(X, Wf, bfp, Wi, bip, Wg, bgp, Wo,
                                           bop, ph, out, flags, hbuf);
}